// Round 2
// baseline (13539.888 us; speedup 1.0000x reference)
//
#include <hip/hip_runtime.h>
#include <cmath>

// Problem constants (from reference)
constexpr int K_H   = 4096;    // hidden
constexpr int V_N   = 32000;   // vocab
constexpr int M_TOK = 4096;    // 8 * 512 tokens
constexpr int T_SEQ = 512;
constexpr int NPAIRS = 4;
constexpr float BETA = 0.1f;
constexpr int IGNORE_IDX = -100;   // target arrives as int32 from the harness

// GEMM tiling
constexpr int BM = 128, BN = 128, BK = 16, PAD = 4;
constexpr int NBLK = V_N / BN;   // 250 n-tiles

// ---------------------------------------------------------------------------
// Fused GEMM + per-tile row max / sum(exp) partials.
// A = x  [M_TOK, K_H] row-major; B = weight [V_N, K_H] row-major (NT gemm).
// Writes pmax[nb*M_TOK + m], psum[nb*M_TOK + m].
// ---------------------------------------------------------------------------
__global__ __launch_bounds__(256)
void gemm_lse_kernel(const float* __restrict__ A, const float* __restrict__ B,
                     float* __restrict__ pmax, float* __restrict__ psum)
{
    __shared__ float As[BK][BM + PAD];
    __shared__ float Bs[BK][BN + PAD];

    const int tid = threadIdx.x;
    const int tx  = tid & 15;    // col group (8 cols each)
    const int ty  = tid >> 4;    // row group (8 rows each)
    const int m0  = blockIdx.x * BM;   // m fastest: keeps x L3-resident, W streams once
    const int n0  = blockIdx.y * BN;

    // Global staging mapping: r = tid>>2 (tile row 0..63, +64), c = tid&3
    const int r0 = tid >> 2;
    const int c0 = tid & 3;
    const float* Ap0 = A + (size_t)(m0 + r0)      * K_H + c0 * 4;
    const float* Ap1 = A + (size_t)(m0 + r0 + 64) * K_H + c0 * 4;
    const float* Bp0 = B + (size_t)(n0 + r0)      * K_H + c0 * 4;
    const float* Bp1 = B + (size_t)(n0 + r0 + 64) * K_H + c0 * 4;

    float acc[8][8];
#pragma unroll
    for (int i = 0; i < 8; ++i)
#pragma unroll
        for (int j = 0; j < 8; ++j) acc[i][j] = 0.0f;

    // Prologue: load k-tile 0
    float4 a0 = *(const float4*)(Ap0);
    float4 a1 = *(const float4*)(Ap1);
    float4 b0 = *(const float4*)(Bp0);
    float4 b1 = *(const float4*)(Bp1);

    for (int kt = 0; kt < K_H; kt += BK) {
        // regs -> LDS (transposed: As[k][m])
        const int kc = c0 * 4;
        As[kc + 0][r0] = a0.x; As[kc + 1][r0] = a0.y; As[kc + 2][r0] = a0.z; As[kc + 3][r0] = a0.w;
        As[kc + 0][r0 + 64] = a1.x; As[kc + 1][r0 + 64] = a1.y; As[kc + 2][r0 + 64] = a1.z; As[kc + 3][r0 + 64] = a1.w;
        Bs[kc + 0][r0] = b0.x; Bs[kc + 1][r0] = b0.y; Bs[kc + 2][r0] = b0.z; Bs[kc + 3][r0] = b0.w;
        Bs[kc + 0][r0 + 64] = b1.x; Bs[kc + 1][r0 + 64] = b1.y; Bs[kc + 2][r0 + 64] = b1.z; Bs[kc + 3][r0 + 64] = b1.w;
        __syncthreads();

        // Prefetch next k-tile while computing this one
        if (kt + BK < K_H) {
            a0 = *(const float4*)(Ap0 + kt + BK);
            a1 = *(const float4*)(Ap1 + kt + BK);
            b0 = *(const float4*)(Bp0 + kt + BK);
            b1 = *(const float4*)(Bp1 + kt + BK);
        }

#pragma unroll
        for (int kk = 0; kk < BK; ++kk) {
            const float4 va0 = *(const float4*)&As[kk][ty * 8];
            const float4 va1 = *(const float4*)&As[kk][ty * 8 + 4];
            const float4 vb0 = *(const float4*)&Bs[kk][tx * 8];
            const float4 vb1 = *(const float4*)&Bs[kk][tx * 8 + 4];
            float av[8] = {va0.x, va0.y, va0.z, va0.w, va1.x, va1.y, va1.z, va1.w};
            float bv[8] = {vb0.x, vb0.y, vb0.z, vb0.w, vb1.x, vb1.y, vb1.z, vb1.w};
#pragma unroll
            for (int i = 0; i < 8; ++i)
#pragma unroll
                for (int j = 0; j < 8; ++j)
                    acc[i][j] = fmaf(av[i], bv[j], acc[i][j]);
        }
        __syncthreads();
    }

    // Epilogue: per-row max + sum(exp) over this 128-col tile.
    // Row r = m0 + ty*8 + i; row-mates = 16 consecutive lanes sharing ty
    // (one wave) -> 16-lane xor shuffle reduce.
#pragma unroll
    for (int i = 0; i < 8; ++i) {
        float mx = acc[i][0];
#pragma unroll
        for (int j = 1; j < 8; ++j) mx = fmaxf(mx, acc[i][j]);
        for (int off = 8; off > 0; off >>= 1)
            mx = fmaxf(mx, __shfl_xor(mx, off, 64));

        float s = 0.0f;
#pragma unroll
        for (int j = 0; j < 8; ++j) s += expf(acc[i][j] - mx);
        for (int off = 8; off > 0; off >>= 1)
            s += __shfl_xor(s, off, 64);

        if (tx == 0) {
            const size_t idx = (size_t)blockIdx.y * M_TOK + (m0 + ty * 8 + i);
            pmax[idx] = mx;
            psum[idx] = s;
        }
    }
}

// ---------------------------------------------------------------------------
// Per-token target logit: tdot[m] = dot(x[m,:], W[target[m],:])
// target is int32 (harness passes integer inputs as int).
// ---------------------------------------------------------------------------
__global__ __launch_bounds__(256)
void tdot_kernel(const float* __restrict__ x, const float* __restrict__ w,
                 const int* __restrict__ tgt, float* __restrict__ tdot)
{
    const int m = blockIdx.x;
    const int lbl = tgt[m];
    const int label = (lbl == IGNORE_IDX) ? 0 : lbl;

    const float4* xr = (const float4*)(x + (size_t)m * K_H);
    const float4* wr = (const float4*)(w + (size_t)label * K_H);
    float s = 0.0f;
    for (int i = threadIdx.x; i < K_H / 4; i += 256) {
        const float4 a = xr[i];
        const float4 b = wr[i];
        s += a.x * b.x + a.y * b.y + a.z * b.z + a.w * b.w;
    }
    __shared__ float red[256];
    red[threadIdx.x] = s;
    __syncthreads();
    for (int st = 128; st > 0; st >>= 1) {
        if (threadIdx.x < st) red[threadIdx.x] += red[threadIdx.x + st];
        __syncthreads();
    }
    if (threadIdx.x == 0) tdot[m] = red[0];
}

// ---------------------------------------------------------------------------
// Per-batch-row average of per-token logps. One block per batch row (8).
// Double-precision combine of the 250 (max, sumexp) partials per token.
// ---------------------------------------------------------------------------
__global__ __launch_bounds__(256)
void finalize_kernel(const float* __restrict__ pmax, const float* __restrict__ psum,
                     const float* __restrict__ tdot, const int* __restrict__ tgt,
                     double* __restrict__ avg_out)
{
    const int b = blockIdx.x;
    double lsum = 0.0, lcnt = 0.0;

    for (int t = threadIdx.x; t < T_SEQ; t += 256) {
        const int m = b * T_SEQ + t;
        const int lbl = tgt[m];
        if (lbl != IGNORE_IDX) {
            float gmax = -INFINITY;
            for (int nb = 0; nb < NBLK; ++nb)
                gmax = fmaxf(gmax, pmax[(size_t)nb * M_TOK + m]);
            double s = 0.0;
            for (int nb = 0; nb < NBLK; ++nb) {
                const size_t idx = (size_t)nb * M_TOK + m;
                s += (double)psum[idx] * exp((double)pmax[idx] - (double)gmax);
            }
            const double lse = (double)gmax + log(s);
            lsum += (double)tdot[m] - lse;
            lcnt += 1.0;
        }
    }

    __shared__ double rs[256];
    __shared__ double rc[256];
    rs[threadIdx.x] = lsum;
    rc[threadIdx.x] = lcnt;
    __syncthreads();
    for (int st = 128; st > 0; st >>= 1) {
        if (threadIdx.x < st) {
            rs[threadIdx.x] += rs[threadIdx.x + st];
            rc[threadIdx.x] += rc[threadIdx.x + st];
        }
        __syncthreads();
    }
    if (threadIdx.x == 0) avg_out[b] = rs[0] / rc[0];
}

// ---------------------------------------------------------------------------
// Deterministic final scalar (no atomics -> bit-stable across graph replays)
// ---------------------------------------------------------------------------
__global__ void loss_kernel(const double* __restrict__ avg, float* __restrict__ out)
{
    if (threadIdx.x == 0 && blockIdx.x == 0) {
        double acc = 0.0;
        for (int i = 0; i < NPAIRS; ++i) acc += avg[i] - avg[i + NPAIRS];
        out[0] = (float)(-(double)BETA * acc / (double)NPAIRS);
    }
}

// ---------------------------------------------------------------------------
extern "C" void kernel_launch(void* const* d_in, const int* in_sizes, int n_in,
                              void* d_out, int out_size, void* d_ws, size_t ws_size,
                              hipStream_t stream)
{
    const float* x = (const float*)d_in[0];          // [8,512,4096] fp32
    const float* w = (const float*)d_in[1];          // [32000,4096] fp32
    const int* tgt = (const int*)d_in[2];            // [8,512] int32 (harness converts int64 -> int)

    // Workspace layout (floats): pmax [NBLK*M], psum [NBLK*M], tdot [M], avg [8 doubles]
    float* pmax = (float*)d_ws;
    float* psum = pmax + (size_t)NBLK * M_TOK;
    float* tdot = psum + (size_t)NBLK * M_TOK;
    double* avg = (double*)(tdot + M_TOK);   // byte offset 8,208,384 — 8-aligned

    dim3 grid(M_TOK / BM, V_N / BN);   // (32, 250), m fastest for W streaming
    gemm_lse_kernel<<<grid, 256, 0, stream>>>(x, w, pmax, psum);
    tdot_kernel<<<M_TOK, 256, 0, stream>>>(x, w, tgt, tdot);
    finalize_kernel<<<8, 256, 0, stream>>>(pmax, psum, tdot, tgt, avg);
    loss_kernel<<<1, 64, 0, stream>>>(avg, (float*)d_out);
}

// Round 3
// 3717.795 us; speedup vs baseline: 3.6419x; 3.6419x over previous
//
#include <hip/hip_runtime.h>
#include <cmath>

// Problem constants (from reference)
constexpr int K_H   = 4096;    // hidden
constexpr int V_N   = 32000;   // vocab
constexpr int M_TOK = 4096;    // 8 * 512 tokens
constexpr int T_SEQ = 512;
constexpr int NPAIRS = 4;
constexpr float BETA = 0.1f;
constexpr int IGNORE_IDX = -100;   // target arrives as int32 from the harness

constexpr int NBLK = V_N / 128;   // 250 n-tiles

typedef _Float16 h8 __attribute__((ext_vector_type(8)));
typedef _Float16 h4 __attribute__((ext_vector_type(4)));
typedef float    f4 __attribute__((ext_vector_type(4)));

// ---------------------------------------------------------------------------
// async global->LDS 16B (wave-uniform LDS base + lane*16)
// ---------------------------------------------------------------------------
__device__ __forceinline__ void async_copy16(void* lds, const void* g) {
    __builtin_amdgcn_global_load_lds(
        (const __attribute__((address_space(1))) unsigned int*)g,
        (__attribute__((address_space(3))) unsigned int*)lds, 16, 0, 0);
}

// ---------------------------------------------------------------------------
// fp32 -> (f16 hi, f16 lo) plane conversion, float4-vectorized
// ---------------------------------------------------------------------------
__global__ __launch_bounds__(256)
void convert_kernel(const float* __restrict__ src, _Float16* __restrict__ hi,
                    _Float16* __restrict__ lo, int n4)
{
    const int i = blockIdx.x * 256 + threadIdx.x;
    if (i >= n4) return;
    const float4 v = ((const float4*)src)[i];
    h4 h, l;
    h.x = (_Float16)v.x; l.x = (_Float16)(v.x - (float)h.x);
    h.y = (_Float16)v.y; l.y = (_Float16)(v.y - (float)h.y);
    h.z = (_Float16)v.z; l.z = (_Float16)(v.z - (float)h.z);
    h.w = (_Float16)v.w; l.w = (_Float16)(v.w - (float)h.w);
    ((h4*)hi)[i] = h;
    ((h4*)lo)[i] = l;
}

// ---------------------------------------------------------------------------
// MFMA split-f16 GEMM + fused per-tile row max / sum(exp).
// A planes xh/xl [M_TOK,K_H] halves; B planes wh/wl [V_N,K_H] halves.
// 128x128 tile, BK=64, 4 waves each 64x64 (4x4 of 16x16x32 f16 MFMA).
// acc += Ah*Bh + Ah*Bl + Al*Bh  (xl*wl dropped: <=2^-22 rel per product).
// LDS staged via global_load_lds(16B) with XOR-octet swizzle:
//   slot s of row r holds k-octet o = s ^ (r&7)  -> conflict-free reads
//   with tight (unpadded) 64-half rows.
// ---------------------------------------------------------------------------
__global__ __launch_bounds__(256, 2)
void gemm_mfma_lse(const _Float16* __restrict__ xh, const _Float16* __restrict__ xl,
                   const _Float16* __restrict__ wh, const _Float16* __restrict__ wl,
                   float* __restrict__ pmax, float* __restrict__ psum)
{
    __shared__ _Float16 Ah[128 * 64];
    __shared__ _Float16 Al[128 * 64];
    __shared__ _Float16 Bh[128 * 64];
    __shared__ _Float16 Bl[128 * 64];
    __shared__ float redm[2][128];
    __shared__ float reds[2][128];

    const int tid  = threadIdx.x;
    const int wave = tid >> 6;
    const int lane = tid & 63;
    const int g    = lane >> 4;   // k-octet group for fragments
    const int m16  = lane & 15;

    const int m0 = blockIdx.x * 128;   // m fastest in grid -> W tile reuse
    const int n0 = blockIdx.y * 128;
    const int wm = (wave >> 1) * 64;
    const int wn = (wave & 1) * 64;

    // --- staging geometry -------------------------------------------------
    // wave handles tile rows [wave*32, wave*32+32) per plane, 4 instrs x 8 rows.
    // lane l -> row offset l>>3, slot l&7; fetch octet o = (l&7) ^ (l>>3).
    const int lrow = lane >> 3;
    const int oswz = (lane & 7) ^ lrow;
    const int rbase = wave * 32;

    const _Float16* pAh = xh + (size_t)(m0 + rbase + lrow) * K_H + oswz * 8;
    const _Float16* pAl = xl + (size_t)(m0 + rbase + lrow) * K_H + oswz * 8;
    const _Float16* pBh = wh + (size_t)(n0 + rbase + lrow) * K_H + oswz * 8;
    const _Float16* pBl = wl + (size_t)(n0 + rbase + lrow) * K_H + oswz * 8;

    f4 acc[4][4];
#pragma unroll
    for (int i = 0; i < 4; ++i)
#pragma unroll
        for (int j = 0; j < 4; ++j) acc[i][j] = (f4){0.f, 0.f, 0.f, 0.f};

    for (int kt = 0; kt < K_H; kt += 64) {
        __syncthreads();   // LDS reuse: previous chunk's reads complete
#pragma unroll
        for (int i = 0; i < 4; ++i) {
            const size_t go = (size_t)(i * 8) * K_H + kt;
            const int    lo = (rbase + i * 8) * 64;   // halves
            async_copy16(&Ah[lo], pAh + go);
            async_copy16(&Al[lo], pAl + go);
            async_copy16(&Bh[lo], pBh + go);
            async_copy16(&Bl[lo], pBl + go);
        }
        __syncthreads();   // drains vmcnt -> LDS valid

#pragma unroll
        for (int ks = 0; ks < 2; ++ks) {
            h8 ahf[4], alf[4], bhf[4], blf[4];
#pragma unroll
            for (int t = 0; t < 4; ++t) {
                const int arow = wm + t * 16 + m16;
                const int aoct = (ks * 4 + g) ^ (arow & 7);
                const int aoff = arow * 64 + aoct * 8;
                ahf[t] = *(const h8*)&Ah[aoff];
                alf[t] = *(const h8*)&Al[aoff];
                const int brow = wn + t * 16 + m16;
                const int boct = (ks * 4 + g) ^ (brow & 7);
                const int boff = brow * 64 + boct * 8;
                bhf[t] = *(const h8*)&Bh[boff];
                blf[t] = *(const h8*)&Bl[boff];
            }
#pragma unroll
            for (int mi = 0; mi < 4; ++mi)
#pragma unroll
                for (int nj = 0; nj < 4; ++nj) {
                    acc[mi][nj] = __builtin_amdgcn_mfma_f32_16x16x32_f16(ahf[mi], bhf[nj], acc[mi][nj], 0, 0, 0);
                    acc[mi][nj] = __builtin_amdgcn_mfma_f32_16x16x32_f16(ahf[mi], blf[nj], acc[mi][nj], 0, 0, 0);
                    acc[mi][nj] = __builtin_amdgcn_mfma_f32_16x16x32_f16(alf[mi], bhf[nj], acc[mi][nj], 0, 0, 0);
                }
        }
    }

    // --- epilogue: per-row (M) max & sum(exp) over this wave's 64 cols ----
    // C/D layout (m89): col = lane&15 (n), row = (lane>>4)*4 + reg (m).
    // Row-mates = 16 consecutive lanes of quarter g -> xor-shuffle width 16.
#pragma unroll
    for (int mi = 0; mi < 4; ++mi) {
#pragma unroll
        for (int r = 0; r < 4; ++r) {
            float v0 = acc[mi][0][r], v1 = acc[mi][1][r];
            float v2 = acc[mi][2][r], v3 = acc[mi][3][r];
            float mx = fmaxf(fmaxf(v0, v1), fmaxf(v2, v3));
#pragma unroll
            for (int off = 8; off > 0; off >>= 1)
                mx = fmaxf(mx, __shfl_xor(mx, off, 64));
            float s = expf(v0 - mx) + expf(v1 - mx) + expf(v2 - mx) + expf(v3 - mx);
#pragma unroll
            for (int off = 8; off > 0; off >>= 1)
                s += __shfl_xor(s, off, 64);
            if (m16 == 0) {
                const int row = wm + mi * 16 + g * 4 + r;
                redm[wave & 1][row] = mx;
                reds[wave & 1][row] = s;
            }
        }
    }
    __syncthreads();

    // combine the two 64-col halves, write partials [nb][m]
    if (tid < 128) {
        const float m0v = redm[0][tid], m1v = redm[1][tid];
        const float mx = fmaxf(m0v, m1v);
        const float s  = reds[0][tid] * expf(m0v - mx) + reds[1][tid] * expf(m1v - mx);
        const size_t idx = (size_t)blockIdx.y * M_TOK + (m0 + tid);
        pmax[idx] = mx;
        psum[idx] = s;
    }
}

// ---------------------------------------------------------------------------
// Fallback fp32 GEMM+LSE (R1, passing) — used only if ws_size is too small
// ---------------------------------------------------------------------------
__global__ __launch_bounds__(256)
void gemm_lse_kernel(const float* __restrict__ A, const float* __restrict__ B,
                     float* __restrict__ pmax, float* __restrict__ psum)
{
    constexpr int BK = 16, PAD = 4;
    __shared__ float As[BK][128 + PAD];
    __shared__ float Bs[BK][128 + PAD];

    const int tid = threadIdx.x;
    const int tx  = tid & 15;
    const int ty  = tid >> 4;
    const int m0  = blockIdx.x * 128;
    const int n0  = blockIdx.y * 128;
    const int r0  = tid >> 2;
    const int c0  = tid & 3;
    const float* Ap0 = A + (size_t)(m0 + r0)      * K_H + c0 * 4;
    const float* Ap1 = A + (size_t)(m0 + r0 + 64) * K_H + c0 * 4;
    const float* Bp0 = B + (size_t)(n0 + r0)      * K_H + c0 * 4;
    const float* Bp1 = B + (size_t)(n0 + r0 + 64) * K_H + c0 * 4;

    float acc[8][8];
#pragma unroll
    for (int i = 0; i < 8; ++i)
#pragma unroll
        for (int j = 0; j < 8; ++j) acc[i][j] = 0.0f;

    float4 a0 = *(const float4*)(Ap0);
    float4 a1 = *(const float4*)(Ap1);
    float4 b0 = *(const float4*)(Bp0);
    float4 b1 = *(const float4*)(Bp1);

    for (int kt = 0; kt < K_H; kt += BK) {
        const int kc = c0 * 4;
        As[kc + 0][r0] = a0.x; As[kc + 1][r0] = a0.y; As[kc + 2][r0] = a0.z; As[kc + 3][r0] = a0.w;
        As[kc + 0][r0 + 64] = a1.x; As[kc + 1][r0 + 64] = a1.y; As[kc + 2][r0 + 64] = a1.z; As[kc + 3][r0 + 64] = a1.w;
        Bs[kc + 0][r0] = b0.x; Bs[kc + 1][r0] = b0.y; Bs[kc + 2][r0] = b0.z; Bs[kc + 3][r0] = b0.w;
        Bs[kc + 0][r0 + 64] = b1.x; Bs[kc + 1][r0 + 64] = b1.y; Bs[kc + 2][r0 + 64] = b1.z; Bs[kc + 3][r0 + 64] = b1.w;
        __syncthreads();
        if (kt + BK < K_H) {
            a0 = *(const float4*)(Ap0 + kt + BK);
            a1 = *(const float4*)(Ap1 + kt + BK);
            b0 = *(const float4*)(Bp0 + kt + BK);
            b1 = *(const float4*)(Bp1 + kt + BK);
        }
#pragma unroll
        for (int kk = 0; kk < BK; ++kk) {
            const float4 va0 = *(const float4*)&As[kk][ty * 8];
            const float4 va1 = *(const float4*)&As[kk][ty * 8 + 4];
            const float4 vb0 = *(const float4*)&Bs[kk][tx * 8];
            const float4 vb1 = *(const float4*)&Bs[kk][tx * 8 + 4];
            float av[8] = {va0.x, va0.y, va0.z, va0.w, va1.x, va1.y, va1.z, va1.w};
            float bv[8] = {vb0.x, vb0.y, vb0.z, vb0.w, vb1.x, vb1.y, vb1.z, vb1.w};
#pragma unroll
            for (int i = 0; i < 8; ++i)
#pragma unroll
                for (int j = 0; j < 8; ++j)
                    acc[i][j] = fmaf(av[i], bv[j], acc[i][j]);
        }
        __syncthreads();
    }

#pragma unroll
    for (int i = 0; i < 8; ++i) {
        float mx = acc[i][0];
#pragma unroll
        for (int j = 1; j < 8; ++j) mx = fmaxf(mx, acc[i][j]);
        for (int off = 8; off > 0; off >>= 1)
            mx = fmaxf(mx, __shfl_xor(mx, off, 64));
        float s = 0.0f;
#pragma unroll
        for (int j = 0; j < 8; ++j) s += expf(acc[i][j] - mx);
        for (int off = 8; off > 0; off >>= 1)
            s += __shfl_xor(s, off, 64);
        if (tx == 0) {
            const size_t idx = (size_t)blockIdx.y * M_TOK + (m0 + ty * 8 + i);
            pmax[idx] = mx;
            psum[idx] = s;
        }
    }
}

// ---------------------------------------------------------------------------
// Per-token target logit: tdot[m] = dot(x[m,:], W[target[m],:])  (exact fp32)
// ---------------------------------------------------------------------------
__global__ __launch_bounds__(256)
void tdot_kernel(const float* __restrict__ x, const float* __restrict__ w,
                 const int* __restrict__ tgt, float* __restrict__ tdot)
{
    const int m = blockIdx.x;
    const int lbl = tgt[m];
    const int label = (lbl == IGNORE_IDX) ? 0 : lbl;

    const float4* xr = (const float4*)(x + (size_t)m * K_H);
    const float4* wr = (const float4*)(w + (size_t)label * K_H);
    float s = 0.0f;
    for (int i = threadIdx.x; i < K_H / 4; i += 256) {
        const float4 a = xr[i];
        const float4 b = wr[i];
        s += a.x * b.x + a.y * b.y + a.z * b.z + a.w * b.w;
    }
    __shared__ float red[256];
    red[threadIdx.x] = s;
    __syncthreads();
    for (int st = 128; st > 0; st >>= 1) {
        if (threadIdx.x < st) red[threadIdx.x] += red[threadIdx.x + st];
        __syncthreads();
    }
    if (threadIdx.x == 0) tdot[m] = red[0];
}

// ---------------------------------------------------------------------------
// Per-batch-row average of per-token logps (double online-softmax combine)
// ---------------------------------------------------------------------------
__global__ __launch_bounds__(256)
void finalize_kernel(const float* __restrict__ pmax, const float* __restrict__ psum,
                     const float* __restrict__ tdot, const int* __restrict__ tgt,
                     double* __restrict__ avg_out)
{
    const int b = blockIdx.x;
    double lsum = 0.0, lcnt = 0.0;

    for (int t = threadIdx.x; t < T_SEQ; t += 256) {
        const int m = b * T_SEQ + t;
        const int lbl = tgt[m];
        if (lbl != IGNORE_IDX) {
            float gmax = -INFINITY;
            for (int nb = 0; nb < NBLK; ++nb)
                gmax = fmaxf(gmax, pmax[(size_t)nb * M_TOK + m]);
            double s = 0.0;
            for (int nb = 0; nb < NBLK; ++nb) {
                const size_t idx = (size_t)nb * M_TOK + m;
                s += (double)psum[idx] * exp((double)pmax[idx] - (double)gmax);
            }
            const double lse = (double)gmax + log(s);
            lsum += (double)tdot[m] - lse;
            lcnt += 1.0;
        }
    }

    __shared__ double rs[256];
    __shared__ double rc[256];
    rs[threadIdx.x] = lsum;
    rc[threadIdx.x] = lcnt;
    __syncthreads();
    for (int st = 128; st > 0; st >>= 1) {
        if (threadIdx.x < st) {
            rs[threadIdx.x] += rs[threadIdx.x + st];
            rc[threadIdx.x] += rc[threadIdx.x + st];
        }
        __syncthreads();
    }
    if (threadIdx.x == 0) avg_out[b] = rs[0] / rc[0];
}

// ---------------------------------------------------------------------------
// Deterministic final scalar
// ---------------------------------------------------------------------------
__global__ void loss_kernel(const double* __restrict__ avg, float* __restrict__ out)
{
    if (threadIdx.x == 0 && blockIdx.x == 0) {
        double acc = 0.0;
        for (int i = 0; i < NPAIRS; ++i) acc += avg[i] - avg[i + NPAIRS];
        out[0] = (float)(-(double)BETA * acc / (double)NPAIRS);
    }
}

// ---------------------------------------------------------------------------
extern "C" void kernel_launch(void* const* d_in, const int* in_sizes, int n_in,
                              void* d_out, int out_size, void* d_ws, size_t ws_size,
                              hipStream_t stream)
{
    const float* x = (const float*)d_in[0];          // [8,512,4096] fp32
    const float* w = (const float*)d_in[1];          // [32000,4096] fp32
    const int* tgt = (const int*)d_in[2];            // [8,512] int32

    const size_t xplane = (size_t)M_TOK * K_H;       // 16,777,216 halves
    const size_t wplane = (size_t)V_N * K_H;         // 131,072,000 halves

    // fast-path workspace layout
    _Float16* xh = (_Float16*)d_ws;
    _Float16* xl = xh + xplane;
    _Float16* wh = xl + xplane;
    _Float16* wl = wh + wplane;
    float* pmaxF = (float*)(wl + wplane);
    float* psumF = pmaxF + (size_t)NBLK * M_TOK;
    float* tdotF = psumF + (size_t)NBLK * M_TOK;
    double* avgF = (double*)(tdotF + M_TOK);
    const size_t need = (size_t)((char*)(avgF + 8) - (char*)d_ws);

    if (ws_size >= need) {
        // convert planes
        const int xn4 = (int)(xplane / 4);
        const int wn4 = (int)(wplane / 4);
        convert_kernel<<<(xn4 + 255) / 256, 256, 0, stream>>>(x, xh, xl, xn4);
        convert_kernel<<<(wn4 + 255) / 256, 256, 0, stream>>>(w, wh, wl, wn4);

        dim3 grid(M_TOK / 128, V_N / 128);   // (32, 250), m fastest
        gemm_mfma_lse<<<grid, 256, 0, stream>>>(xh, xl, wh, wl, pmaxF, psumF);
        tdot_kernel<<<M_TOK, 256, 0, stream>>>(x, w, tgt, tdotF);
        finalize_kernel<<<8, 256, 0, stream>>>(pmaxF, psumF, tdotF, tgt, avgF);
        loss_kernel<<<1, 64, 0, stream>>>(avgF, (float*)d_out);
    } else {
        // fallback: fp32 pipeline (needs ~8.2 MB)
        float* pmax = (float*)d_ws;
        float* psum = pmax + (size_t)NBLK * M_TOK;
        float* tdot = psum + (size_t)NBLK * M_TOK;
        double* avg = (double*)(tdot + M_TOK);
        dim3 grid(M_TOK / 128, V_N / 128);
        gemm_lse_kernel<<<grid, 256, 0, stream>>>(x, w, pmax, psum);
        tdot_kernel<<<M_TOK, 256, 0, stream>>>(x, w, tgt, tdot);
        finalize_kernel<<<8, 256, 0, stream>>>(pmax, psum, tdot, tgt, avg);
        loss_kernel<<<1, 64, 0, stream>>>(avg, (float*)d_out);
    }
}